// Round 1
// baseline (666.719 us; speedup 1.0000x reference)
//
#include <hip/hip_runtime.h>

#define HW 129600
#define WG 360
#define HG 360
#define NCLS 10
#define NPROP 200
#define CDIM 128
#define NROWS 80000
#define NB 2
#define CAND_CAP 400000
#define SEL_CAP 4096

// ---------------------------------------------------------------------------
// K1: fused MLP head. Per block: 32 rows x 128 cols, K-chunks of 32 in LDS.
// Each thread (tc=col group of 4, tr=row group of 8) holds acc[8][4].
// Epilogue: h=relu(acc+b1) -> LDS (reuse W tile), hm = h@W2+b2, heat=sigmoid,
// scattered into dense_heat; also writes rowmap for the qf gather.
// ---------------------------------------------------------------------------
__global__ __launch_bounds__(128) void k_head(
    const float* __restrict__ feat, const float* __restrict__ W1,
    const float* __restrict__ b1, const float* __restrict__ W2,
    const float* __restrict__ b2, const int* __restrict__ idxs,
    float* __restrict__ dense_heat, int* __restrict__ rowmap) {
  __shared__ __align__(16) float lds_w[32 * 128];     // W1 chunk; reused for h
  __shared__ __align__(16) float lds_f[32 * 32];
  __shared__ __align__(16) float lds_w2t[NCLS * 128]; // W2 transposed [j][k]
  __shared__ int lds_b[32];
  __shared__ int lds_p[32];
  const int tid = threadIdx.x;
  const int row0 = blockIdx.x * 32;
  const int tc = tid & 31;
  const int tr = tid >> 5;

  float acc[8][4];
#pragma unroll
  for (int r = 0; r < 8; ++r) {
#pragma unroll
    for (int c = 0; c < 4; ++c) acc[r][c] = 0.f;
  }

  for (int kt = 0; kt < 4; ++kt) {
#pragma unroll
    for (int i = 0; i < 8; ++i) {
      int fi = tid + i * 128;
      *(float4*)(lds_w + fi * 4) = *(const float4*)(W1 + kt * 4096 + fi * 4);
    }
#pragma unroll
    for (int i = 0; i < 2; ++i) {
      int fi = tid + i * 128;
      int r = fi >> 3, kq = fi & 7;
      *(float4*)(lds_f + r * 32 + kq * 4) =
          *(const float4*)(feat + (size_t)(row0 + r) * CDIM + kt * 32 + kq * 4);
    }
    __syncthreads();
#pragma unroll
    for (int kg = 0; kg < 8; ++kg) {
      float4 w0 = *(const float4*)(lds_w + (kg * 4 + 0) * 128 + tc * 4);
      float4 w1 = *(const float4*)(lds_w + (kg * 4 + 1) * 128 + tc * 4);
      float4 w2 = *(const float4*)(lds_w + (kg * 4 + 2) * 128 + tc * 4);
      float4 w3 = *(const float4*)(lds_w + (kg * 4 + 3) * 128 + tc * 4);
#pragma unroll
      for (int r = 0; r < 8; ++r) {
        float4 fv = *(const float4*)(lds_f + (tr * 8 + r) * 32 + kg * 4);
        acc[r][0] = fmaf(fv.x, w0.x, acc[r][0]);
        acc[r][0] = fmaf(fv.y, w1.x, acc[r][0]);
        acc[r][0] = fmaf(fv.z, w2.x, acc[r][0]);
        acc[r][0] = fmaf(fv.w, w3.x, acc[r][0]);
        acc[r][1] = fmaf(fv.x, w0.y, acc[r][1]);
        acc[r][1] = fmaf(fv.y, w1.y, acc[r][1]);
        acc[r][1] = fmaf(fv.z, w2.y, acc[r][1]);
        acc[r][1] = fmaf(fv.w, w3.y, acc[r][1]);
        acc[r][2] = fmaf(fv.x, w0.z, acc[r][2]);
        acc[r][2] = fmaf(fv.y, w1.z, acc[r][2]);
        acc[r][2] = fmaf(fv.z, w2.z, acc[r][2]);
        acc[r][2] = fmaf(fv.w, w3.z, acc[r][2]);
        acc[r][3] = fmaf(fv.x, w0.w, acc[r][3]);
        acc[r][3] = fmaf(fv.y, w1.w, acc[r][3]);
        acc[r][3] = fmaf(fv.z, w2.w, acc[r][3]);
        acc[r][3] = fmaf(fv.w, w3.w, acc[r][3]);
      }
    }
    __syncthreads();
  }

  // h = relu(acc + b1) into lds_w (freed by the barrier above)
  float4 b1v = *(const float4*)(b1 + tc * 4);
#pragma unroll
  for (int r = 0; r < 8; ++r) {
    float4 h;
    h.x = fmaxf(acc[r][0] + b1v.x, 0.f);
    h.y = fmaxf(acc[r][1] + b1v.y, 0.f);
    h.z = fmaxf(acc[r][2] + b1v.z, 0.f);
    h.w = fmaxf(acc[r][3] + b1v.w, 0.f);
    *(float4*)(lds_w + (tr * 8 + r) * 128 + tc * 4) = h;
  }
  for (int i = tid; i < CDIM * NCLS; i += 128) {
    int k = i / NCLS, j = i - k * NCLS;
    lds_w2t[j * 128 + k] = W2[i];
  }
  if (tid < 32) {
    int row = row0 + tid;
    int bb = idxs[row * 3 + 0];
    int yy = idxs[row * 3 + 1];
    int xx = idxs[row * 3 + 2];
    lds_b[tid] = bb;
    lds_p[tid] = yy * WG + xx;
    rowmap[(size_t)bb * HW + yy * WG + xx] = row;
  }
  __syncthreads();

  // layer 2: 320 outputs (32 rows x 10 classes) over 128 threads.
  // k-rotation by tid keeps LDS banks spread (conflict-free-ish b128 reads).
#pragma unroll
  for (int oo = 0; oo < 3; ++oo) {
    int o = tid + oo * 128;
    if (o < 32 * NCLS) {
      int r = o / NCLS, j = o - r * NCLS;
      float s = b2[j];
      for (int i4 = 0; i4 < 32; ++i4) {
        int k4 = (i4 + tid) & 31;
        float4 hv = *(const float4*)(lds_w + r * 128 + k4 * 4);
        float4 wv = *(const float4*)(lds_w2t + j * 128 + k4 * 4);
        s = fmaf(hv.x, wv.x, s);
        s = fmaf(hv.y, wv.y, s);
        s = fmaf(hv.z, wv.z, s);
        s = fmaf(hv.w, wv.w, s);
      }
      float heat = 1.0f / (1.0f + expf(-s));
      dense_heat[((size_t)lds_b[r] * NCLS + j) * HW + lds_p[r]] = heat;
    }
  }
}

// ---------------------------------------------------------------------------
// K2: 3x3 NMS over dense heat + wave-aggregated candidate compaction +
// 16-bit-prefix histogram for the top-k threshold select.
// ---------------------------------------------------------------------------
__global__ __launch_bounds__(256) void k_nms(
    const float* __restrict__ dense_heat, unsigned long long* __restrict__ cand,
    int* __restrict__ cand_cnt, unsigned int* __restrict__ hist) {
  const int pos = blockIdx.x * 256 + threadIdx.x;
  const int cl = blockIdx.y;
  const int b = blockIdx.z;
  if (pos >= HW) return;
  const float* hp = dense_heat + ((size_t)b * NCLS + cl) * HW;
  float v = hp[pos];
  int y = pos / WG;
  int x = pos - y * WG;
  float out;
  if (cl >= 8) {
    out = v;  // classes 8,9: no NMS
  } else if (y == 0 || y == HG - 1 || x == 0 || x == WG - 1) {
    out = 0.f;  // border: local_max stays 0 -> suppressed (v>0) or already 0
  } else {
    float m = v;
    m = fmaxf(m, hp[pos - 1]);
    m = fmaxf(m, hp[pos + 1]);
    m = fmaxf(m, hp[pos - WG - 1]);
    m = fmaxf(m, hp[pos - WG]);
    m = fmaxf(m, hp[pos - WG + 1]);
    m = fmaxf(m, hp[pos + WG - 1]);
    m = fmaxf(m, hp[pos + WG]);
    m = fmaxf(m, hp[pos + WG + 1]);
    out = (v == m) ? v : 0.f;
  }
  bool pred = out > 0.f;
  unsigned long long mask = __ballot(pred);
  if (pred) {
    unsigned int bits = __float_as_uint(out);
    atomicAdd(&hist[((size_t)b << 16) + (bits >> 16)], 1u);
    int lane = threadIdx.x & 63;
    int lb = __popcll(mask & ((1ull << lane) - 1ull));
    unsigned int base = 0;
    if (lb == 0) base = (unsigned int)atomicAdd(&cand_cnt[b], (int)__popcll(mask));
    base = (unsigned int)__builtin_amdgcn_readfirstlane((int)base);
    unsigned int gidx = (unsigned int)cl * HW + (unsigned int)pos;
    // key: heat bits desc, then smaller gidx first (jax top_k tie-break)
    unsigned long long key =
        ((unsigned long long)bits << 32) | (unsigned long long)(~gidx);
    unsigned int slot = base + (unsigned int)lb;
    if (slot < CAND_CAP) cand[(size_t)b * CAND_CAP + slot] = key;
  }
}

// ---------------------------------------------------------------------------
// K3a: find 16-bit-prefix threshold bin T: count(prefix >= T) >= 200,
//      count(prefix > T) < 200.
// ---------------------------------------------------------------------------
__global__ __launch_bounds__(256) void k_thresh(
    const unsigned int* __restrict__ hist, int* __restrict__ selT) {
  __shared__ unsigned int coarse[256];
  const int b = blockIdx.x;
  const unsigned int* h = hist + ((size_t)b << 16);
  unsigned int s = 0;
  for (int i = 0; i < 256; ++i) s += h[threadIdx.x * 256 + i];
  coarse[threadIdx.x] = s;
  __syncthreads();
  if (threadIdx.x == 0) {
    unsigned int cum = 0;
    int T = 0;
    int ci = 255;
    for (; ci >= 0; --ci) {
      if (cum + coarse[ci] >= NPROP) break;
      cum += coarse[ci];
    }
    if (ci >= 0) {
      int t = 255;
      for (; t > 0; --t) {
        unsigned int c = h[ci * 256 + t];
        if (cum + c >= NPROP) break;
        cum += c;
      }
      T = ci * 256 + t;
    }
    selT[b] = T;
  }
}

// ---------------------------------------------------------------------------
// K3b: collect all candidates with prefix >= T (typically ~200-400).
// ---------------------------------------------------------------------------
__global__ __launch_bounds__(256) void k_collect(
    const unsigned long long* __restrict__ cand, const int* __restrict__ cand_cnt,
    const int* __restrict__ selT, unsigned long long* __restrict__ sel,
    int* __restrict__ sel_cnt) {
  const int b = blockIdx.y;
  const int i = blockIdx.x * 256 + threadIdx.x;
  if (i >= cand_cnt[b]) return;
  unsigned long long key = cand[(size_t)b * CAND_CAP + i];
  if ((unsigned int)(key >> 48) >= (unsigned int)selT[b]) {
    int p = atomicAdd(&sel_cnt[b], 1);
    if (p < SEL_CAP) sel[(size_t)b * SEL_CAP + p] = key;
  }
}

// ---------------------------------------------------------------------------
// K4: bitonic sort candidates (descending; n = next pow2 >= M, usually 256/512),
// then emit qf / query_pos / qhs / cls for top-200.
// ---------------------------------------------------------------------------
__global__ __launch_bounds__(256) void k_final(
    const unsigned long long* __restrict__ sel, const int* __restrict__ sel_cnt,
    const float* __restrict__ dense_heat, const int* __restrict__ rowmap,
    const float* __restrict__ feat, const float* __restrict__ Wc,
    const float* __restrict__ bc, float* __restrict__ out) {
  __shared__ unsigned long long sk[SEL_CAP];
  const int b = blockIdx.x;
  const int tid = threadIdx.x;
  int M = sel_cnt[b];
  if (M > SEL_CAP) M = SEL_CAP;
  int n = 256;
  while (n < M) n <<= 1;
  for (int i = tid; i < n; i += 256)
    sk[i] = (i < M) ? sel[(size_t)b * SEL_CAP + i] : 0ull;
  __syncthreads();
  for (int k = 2; k <= n; k <<= 1) {
    for (int j = k >> 1; j > 0; j >>= 1) {
      for (int t = tid; t < n; t += 256) {
        int l = t ^ j;
        if (l > t) {
          unsigned long long a = sk[t], c = sk[l];
          bool up = ((t & k) == 0);
          if (up ? (a < c) : (a > c)) {
            sk[t] = c;
            sk[l] = a;
          }
        }
      }
      __syncthreads();
    }
  }
  if (tid < NPROP) {
    const int p = tid;
    unsigned long long key = sk[p];
    unsigned int bits = (unsigned int)(key >> 32);
    unsigned int gidx = ~((unsigned int)(key & 0xFFFFFFFFull));
    if (bits == 0u) gidx = 0u;  // defensive (cannot happen: >=200 positives)
    int cls = (int)(gidx / HW);
    int pos = (int)(gidx - (unsigned int)cls * HW);
    int y = pos / WG, x = pos - y * WG;
    // query_pos (B, NPROP, 2) at offset 51200: bev_pos = (x, y)
    out[51200 + ((size_t)b * NPROP + p) * 2 + 0] = (float)x;
    out[51200 + ((size_t)b * NPROP + p) * 2 + 1] = (float)y;
    // cls (B, NPROP) at offset 56000
    out[56000 + b * NPROP + p] = (float)cls;
    // qhs (B, NCLS, NPROP) at offset 52000: post-NMS heat, recomputed per class
    for (int k = 0; k < NCLS; ++k) {
      const float* hp = dense_heat + ((size_t)b * NCLS + k) * HW;
      float v = hp[pos];
      float o;
      if (k >= 8) {
        o = v;
      } else if (y == 0 || y == HG - 1 || x == 0 || x == WG - 1) {
        o = 0.f;
      } else {
        float m = v;
        m = fmaxf(m, hp[pos - 1]);
        m = fmaxf(m, hp[pos + 1]);
        m = fmaxf(m, hp[pos - WG - 1]);
        m = fmaxf(m, hp[pos - WG]);
        m = fmaxf(m, hp[pos - WG + 1]);
        m = fmaxf(m, hp[pos + WG - 1]);
        m = fmaxf(m, hp[pos + WG]);
        m = fmaxf(m, hp[pos + WG + 1]);
        o = (v == m) ? v : 0.f;
      }
      out[52000 + ((size_t)b * NCLS + k) * NPROP + p] = o;
    }
    // qf (B, C, NPROP) at offset 0
    int row = rowmap[(size_t)b * HW + pos];
    if (bits == 0u) row = 0;  // defensive
    const float* fr = feat + (size_t)row * CDIM;
    for (int c = 0; c < CDIM; ++c) {
      out[((size_t)b * CDIM + c) * NPROP + p] = fr[c] + Wc[c * NCLS + cls] + bc[c];
    }
  }
}

// ---------------------------------------------------------------------------
// ws layout (bytes):
//   [0)            dense_heat  : B*10*HW*4   = 10,368,000
//   [10368000)     cand        : B*400000*8  =  6,400,000
//   [16768000)     hist        : B*65536*4   =    524,288
//   [17292288)     rowmap      : B*HW*4      =  1,036,800
//   [18329088)     sel         : B*4096*8    =     65,536
//   [18394624)     cnts        : cand_cnt[2], sel_cnt[2], selT[2]
// total ~18.4 MB
// ---------------------------------------------------------------------------
extern "C" void kernel_launch(void* const* d_in, const int* in_sizes, int n_in,
                              void* d_out, int out_size, void* d_ws,
                              size_t ws_size, hipStream_t stream) {
  const float* feat = (const float*)d_in[0];
  const float* W1 = (const float*)d_in[1];
  const float* b1 = (const float*)d_in[2];
  const float* W2 = (const float*)d_in[3];
  const float* b2 = (const float*)d_in[4];
  const float* Wc = (const float*)d_in[5];
  const float* bc = (const float*)d_in[6];
  const int* idxs = (const int*)d_in[7];
  float* out = (float*)d_out;

  char* ws = (char*)d_ws;
  float* dense_heat = (float*)(ws + 0);
  unsigned long long* cand = (unsigned long long*)(ws + 10368000);
  unsigned int* hist = (unsigned int*)(ws + 16768000);
  int* rowmap = (int*)(ws + 17292288);
  unsigned long long* sel = (unsigned long long*)(ws + 18329088);
  int* cnts = (int*)(ws + 18394624);
  int* cand_cnt = cnts + 0;
  int* sel_cnt = cnts + 2;
  int* selT = cnts + 4;

  hipMemsetAsync(dense_heat, 0, (size_t)NB * NCLS * HW * sizeof(float), stream);
  hipMemsetAsync(hist, 0, (size_t)NB * 65536 * sizeof(unsigned int), stream);
  hipMemsetAsync(cnts, 0, 6 * sizeof(int), stream);

  k_head<<<NROWS / 32, 128, 0, stream>>>(feat, W1, b1, W2, b2, idxs, dense_heat,
                                         rowmap);
  k_nms<<<dim3((HW + 255) / 256, NCLS, NB), 256, 0, stream>>>(dense_heat, cand,
                                                              cand_cnt, hist);
  k_thresh<<<NB, 256, 0, stream>>>(hist, selT);
  k_collect<<<dim3((CAND_CAP + 255) / 256, NB), 256, 0, stream>>>(
      cand, cand_cnt, selT, sel, sel_cnt);
  k_final<<<NB, 256, 0, stream>>>(sel, sel_cnt, dense_heat, rowmap, feat, Wc, bc,
                                  out);
}

// Round 2
// 204.401 us; speedup vs baseline: 3.2618x; 3.2618x over previous
//
#include <hip/hip_runtime.h>

#define HW 129600
#define WG 360
#define HG 360
#define NCLS 10
#define NPROP 200
#define CDIM 128
#define NROWS 80000
#define NB 2
#define SEL_CAP 4096
#define HIST_BINS 16384   // heat in (0,1]: (bits>>16) <= 0x3F80 = 16256
#define CHUNK 8192

// ---------------------------------------------------------------------------
// Shared NMS value: 3x3 local-max suppression, classes 8/9 pass-through,
// border rows/cols suppressed (reference's local_max stays 0 there).
// ---------------------------------------------------------------------------
__device__ __forceinline__ float nms_val(const float* __restrict__ hp, int pos,
                                         int cl) {
  float v = hp[pos];
  if (cl >= 8) return v;
  int y = pos / WG, x = pos - y * WG;
  if (y == 0 || y == HG - 1 || x == 0 || x == WG - 1) return 0.f;
  float m = v;
  m = fmaxf(m, hp[pos - 1]);
  m = fmaxf(m, hp[pos + 1]);
  m = fmaxf(m, hp[pos - WG - 1]);
  m = fmaxf(m, hp[pos - WG]);
  m = fmaxf(m, hp[pos - WG + 1]);
  m = fmaxf(m, hp[pos + WG - 1]);
  m = fmaxf(m, hp[pos + WG]);
  m = fmaxf(m, hp[pos + WG + 1]);
  return (v == m) ? v : 0.f;
}

// ---------------------------------------------------------------------------
// K1: fused MLP head (unchanged — numerics must stay bit-identical; selection
// currently matches reference with absmax 0.0).
// ---------------------------------------------------------------------------
__global__ __launch_bounds__(128) void k_head(
    const float* __restrict__ feat, const float* __restrict__ W1,
    const float* __restrict__ b1, const float* __restrict__ W2,
    const float* __restrict__ b2, const int* __restrict__ idxs,
    float* __restrict__ dense_heat, int* __restrict__ rowmap) {
  __shared__ __align__(16) float lds_w[32 * 128];     // W1 chunk; reused for h
  __shared__ __align__(16) float lds_f[32 * 32];
  __shared__ __align__(16) float lds_w2t[NCLS * 128]; // W2 transposed [j][k]
  __shared__ int lds_b[32];
  __shared__ int lds_p[32];
  const int tid = threadIdx.x;
  const int row0 = blockIdx.x * 32;
  const int tc = tid & 31;
  const int tr = tid >> 5;

  float acc[8][4];
#pragma unroll
  for (int r = 0; r < 8; ++r) {
#pragma unroll
    for (int c = 0; c < 4; ++c) acc[r][c] = 0.f;
  }

  for (int kt = 0; kt < 4; ++kt) {
#pragma unroll
    for (int i = 0; i < 8; ++i) {
      int fi = tid + i * 128;
      *(float4*)(lds_w + fi * 4) = *(const float4*)(W1 + kt * 4096 + fi * 4);
    }
#pragma unroll
    for (int i = 0; i < 2; ++i) {
      int fi = tid + i * 128;
      int r = fi >> 3, kq = fi & 7;
      *(float4*)(lds_f + r * 32 + kq * 4) =
          *(const float4*)(feat + (size_t)(row0 + r) * CDIM + kt * 32 + kq * 4);
    }
    __syncthreads();
#pragma unroll
    for (int kg = 0; kg < 8; ++kg) {
      float4 w0 = *(const float4*)(lds_w + (kg * 4 + 0) * 128 + tc * 4);
      float4 w1 = *(const float4*)(lds_w + (kg * 4 + 1) * 128 + tc * 4);
      float4 w2 = *(const float4*)(lds_w + (kg * 4 + 2) * 128 + tc * 4);
      float4 w3 = *(const float4*)(lds_w + (kg * 4 + 3) * 128 + tc * 4);
#pragma unroll
      for (int r = 0; r < 8; ++r) {
        float4 fv = *(const float4*)(lds_f + (tr * 8 + r) * 32 + kg * 4);
        acc[r][0] = fmaf(fv.x, w0.x, acc[r][0]);
        acc[r][0] = fmaf(fv.y, w1.x, acc[r][0]);
        acc[r][0] = fmaf(fv.z, w2.x, acc[r][0]);
        acc[r][0] = fmaf(fv.w, w3.x, acc[r][0]);
        acc[r][1] = fmaf(fv.x, w0.y, acc[r][1]);
        acc[r][1] = fmaf(fv.y, w1.y, acc[r][1]);
        acc[r][1] = fmaf(fv.z, w2.y, acc[r][1]);
        acc[r][1] = fmaf(fv.w, w3.y, acc[r][1]);
        acc[r][2] = fmaf(fv.x, w0.z, acc[r][2]);
        acc[r][2] = fmaf(fv.y, w1.z, acc[r][2]);
        acc[r][2] = fmaf(fv.z, w2.z, acc[r][2]);
        acc[r][2] = fmaf(fv.w, w3.z, acc[r][2]);
        acc[r][3] = fmaf(fv.x, w0.w, acc[r][3]);
        acc[r][3] = fmaf(fv.y, w1.w, acc[r][3]);
        acc[r][3] = fmaf(fv.z, w2.w, acc[r][3]);
        acc[r][3] = fmaf(fv.w, w3.w, acc[r][3]);
      }
    }
    __syncthreads();
  }

  float4 b1v = *(const float4*)(b1 + tc * 4);
#pragma unroll
  for (int r = 0; r < 8; ++r) {
    float4 h;
    h.x = fmaxf(acc[r][0] + b1v.x, 0.f);
    h.y = fmaxf(acc[r][1] + b1v.y, 0.f);
    h.z = fmaxf(acc[r][2] + b1v.z, 0.f);
    h.w = fmaxf(acc[r][3] + b1v.w, 0.f);
    *(float4*)(lds_w + (tr * 8 + r) * 128 + tc * 4) = h;
  }
  for (int i = tid; i < CDIM * NCLS; i += 128) {
    int k = i / NCLS, j = i - k * NCLS;
    lds_w2t[j * 128 + k] = W2[i];
  }
  if (tid < 32) {
    int row = row0 + tid;
    int bb = idxs[row * 3 + 0];
    int yy = idxs[row * 3 + 1];
    int xx = idxs[row * 3 + 2];
    lds_b[tid] = bb;
    lds_p[tid] = yy * WG + xx;
    rowmap[(size_t)bb * HW + yy * WG + xx] = row;
  }
  __syncthreads();

#pragma unroll
  for (int oo = 0; oo < 3; ++oo) {
    int o = tid + oo * 128;
    if (o < 32 * NCLS) {
      int r = o / NCLS, j = o - r * NCLS;
      float s = b2[j];
      for (int i4 = 0; i4 < 32; ++i4) {
        int k4 = (i4 + tid) & 31;
        float4 hv = *(const float4*)(lds_w + r * 128 + k4 * 4);
        float4 wv = *(const float4*)(lds_w2t + j * 128 + k4 * 4);
        s = fmaf(hv.x, wv.x, s);
        s = fmaf(hv.y, wv.y, s);
        s = fmaf(hv.z, wv.z, s);
        s = fmaf(hv.w, wv.w, s);
      }
      float heat = 1.0f / (1.0f + expf(-s));
      dense_heat[((size_t)lds_b[r] * NCLS + j) * HW + lds_p[r]] = heat;
    }
  }
}

// ---------------------------------------------------------------------------
// K2: NMS + per-block LDS histogram (16384 bins = 64 KB), flush nonzero bins
// with uncontended fire-and-forget global atomics (<= 32 hits/bin globally).
// No candidate list, no contended counters.
// ---------------------------------------------------------------------------
__global__ __launch_bounds__(256) void k_nms_hist(
    const float* __restrict__ dense_heat, unsigned int* __restrict__ hist) {
  __shared__ unsigned int lh[HIST_BINS];
  const int cl = blockIdx.y;
  const int b = blockIdx.z;
  const int p0 = blockIdx.x * CHUNK;
  for (int i = threadIdx.x; i < HIST_BINS; i += 256) lh[i] = 0;
  __syncthreads();
  const float* hp = dense_heat + ((size_t)b * NCLS + cl) * HW;
  for (int it = 0; it < CHUNK; it += 256) {
    int pos = p0 + it + threadIdx.x;
    if (pos < HW) {
      float out = nms_val(hp, pos, cl);
      if (out > 0.f) atomicAdd(&lh[__float_as_uint(out) >> 16], 1u);
    }
  }
  __syncthreads();
  unsigned int* gh = hist + (size_t)b * HIST_BINS;
  for (int i = threadIdx.x; i < HIST_BINS; i += 256) {
    unsigned int c = lh[i];
    if (c) atomicAdd(&gh[i], c);
  }
}

// ---------------------------------------------------------------------------
// K3: threshold bin T: count(prefix > T) < 200 <= count(prefix >= T).
// ---------------------------------------------------------------------------
__global__ __launch_bounds__(256) void k_thresh(
    const unsigned int* __restrict__ hist, int* __restrict__ selT) {
  __shared__ unsigned int coarse[256];
  const int b = blockIdx.x;
  const unsigned int* h = hist + (size_t)b * HIST_BINS;
  unsigned int s = 0;
  for (int i = 0; i < 64; ++i) s += h[threadIdx.x * 64 + i];
  coarse[threadIdx.x] = s;
  __syncthreads();
  if (threadIdx.x == 0) {
    unsigned int cum = 0;
    int T = 0;
    int ci = 255;
    for (; ci >= 0; --ci) {
      if (cum + coarse[ci] >= NPROP) break;
      cum += coarse[ci];
    }
    if (ci >= 0) {
      int t = 63;
      for (; t > 0; --t) {
        unsigned int c = h[ci * 64 + t];
        if (cum + c >= NPROP) break;
        cum += c;
      }
      T = ci * 64 + t;
    }
    selT[b] = T;
  }
}

// ---------------------------------------------------------------------------
// K4: recompute NMS (dense_heat is L3-resident), collect prefix >= T.
// Only ~200-400 survivors -> a handful of wave-aggregated atomics.
// ---------------------------------------------------------------------------
__global__ __launch_bounds__(256) void k_collect(
    const float* __restrict__ dense_heat, const int* __restrict__ selT,
    unsigned long long* __restrict__ sel, int* __restrict__ sel_cnt) {
  const int cl = blockIdx.y;
  const int b = blockIdx.z;
  const int pos = blockIdx.x * 256 + threadIdx.x;
  float out = 0.f;
  if (pos < HW)
    out = nms_val(dense_heat + ((size_t)b * NCLS + cl) * HW, pos, cl);
  unsigned int bits = __float_as_uint(out);
  bool pred = (out > 0.f) && ((int)(bits >> 16) >= selT[b]);
  unsigned long long mask = __ballot(pred);
  if (pred) {
    int lane = threadIdx.x & 63;
    int lb = __popcll(mask & ((1ull << lane) - 1ull));
    int base = 0;
    if (lb == 0) base = atomicAdd(&sel_cnt[b], (int)__popcll(mask));
    base = __builtin_amdgcn_readfirstlane(base);
    unsigned int gidx = (unsigned int)cl * HW + (unsigned int)pos;
    // key: heat bits desc, then smaller gidx first (jax top_k tie-break)
    unsigned long long key =
        ((unsigned long long)bits << 32) | (unsigned long long)(~gidx);
    int slot = base + lb;
    if (slot < SEL_CAP) sel[(size_t)b * SEL_CAP + slot] = key;
  }
}

// ---------------------------------------------------------------------------
// K5: bitonic sort (descending), emit qf / query_pos / qhs / cls (unchanged).
// ---------------------------------------------------------------------------
__global__ __launch_bounds__(256) void k_final(
    const unsigned long long* __restrict__ sel, const int* __restrict__ sel_cnt,
    const float* __restrict__ dense_heat, const int* __restrict__ rowmap,
    const float* __restrict__ feat, const float* __restrict__ Wc,
    const float* __restrict__ bc, float* __restrict__ out) {
  __shared__ unsigned long long sk[SEL_CAP];
  const int b = blockIdx.x;
  const int tid = threadIdx.x;
  int M = sel_cnt[b];
  if (M > SEL_CAP) M = SEL_CAP;
  int n = 256;
  while (n < M) n <<= 1;
  for (int i = tid; i < n; i += 256)
    sk[i] = (i < M) ? sel[(size_t)b * SEL_CAP + i] : 0ull;
  __syncthreads();
  for (int k = 2; k <= n; k <<= 1) {
    for (int j = k >> 1; j > 0; j >>= 1) {
      for (int t = tid; t < n; t += 256) {
        int l = t ^ j;
        if (l > t) {
          unsigned long long a = sk[t], c = sk[l];
          bool up = ((t & k) == 0);
          if (up ? (a < c) : (a > c)) {
            sk[t] = c;
            sk[l] = a;
          }
        }
      }
      __syncthreads();
    }
  }
  if (tid < NPROP) {
    const int p = tid;
    unsigned long long key = sk[p];
    unsigned int bits = (unsigned int)(key >> 32);
    unsigned int gidx = ~((unsigned int)(key & 0xFFFFFFFFull));
    if (bits == 0u) gidx = 0u;  // defensive
    int cls = (int)(gidx / HW);
    int pos = (int)(gidx - (unsigned int)cls * HW);
    int y = pos / WG, x = pos - y * WG;
    out[51200 + ((size_t)b * NPROP + p) * 2 + 0] = (float)x;
    out[51200 + ((size_t)b * NPROP + p) * 2 + 1] = (float)y;
    out[56000 + b * NPROP + p] = (float)cls;
    for (int k = 0; k < NCLS; ++k) {
      const float* hp = dense_heat + ((size_t)b * NCLS + k) * HW;
      out[52000 + ((size_t)b * NCLS + k) * NPROP + p] = nms_val(hp, pos, k);
    }
    int row = rowmap[(size_t)b * HW + pos];
    if (bits == 0u) row = 0;  // defensive
    const float* fr = feat + (size_t)row * CDIM;
    for (int c = 0; c < CDIM; ++c) {
      out[((size_t)b * CDIM + c) * NPROP + p] = fr[c] + Wc[c * NCLS + cls] + bc[c];
    }
  }
}

// ---------------------------------------------------------------------------
// ws layout (bytes):
//   [0)          dense_heat : B*10*HW*4      = 10,368,000
//   [10368000)   hist       : B*16384*4      =    131,072
//   [10499072)   rowmap     : B*HW*4         =  1,036,800
//   [11535872)   sel        : B*4096*8       =     65,536
//   [11601408)   cnts       : sel_cnt[2], selT[2]
// total ~11.6 MB
// ---------------------------------------------------------------------------
extern "C" void kernel_launch(void* const* d_in, const int* in_sizes, int n_in,
                              void* d_out, int out_size, void* d_ws,
                              size_t ws_size, hipStream_t stream) {
  const float* feat = (const float*)d_in[0];
  const float* W1 = (const float*)d_in[1];
  const float* b1 = (const float*)d_in[2];
  const float* W2 = (const float*)d_in[3];
  const float* b2 = (const float*)d_in[4];
  const float* Wc = (const float*)d_in[5];
  const float* bc = (const float*)d_in[6];
  const int* idxs = (const int*)d_in[7];
  float* out = (float*)d_out;

  char* ws = (char*)d_ws;
  float* dense_heat = (float*)(ws + 0);
  unsigned int* hist = (unsigned int*)(ws + 10368000);
  int* rowmap = (int*)(ws + 10499072);
  unsigned long long* sel = (unsigned long long*)(ws + 11535872);
  int* cnts = (int*)(ws + 11601408);
  int* sel_cnt = cnts + 0;
  int* selT = cnts + 2;

  hipMemsetAsync(dense_heat, 0, (size_t)NB * NCLS * HW * sizeof(float), stream);
  hipMemsetAsync(hist, 0, (size_t)NB * HIST_BINS * sizeof(unsigned int), stream);
  hipMemsetAsync(cnts, 0, 4 * sizeof(int), stream);

  k_head<<<NROWS / 32, 128, 0, stream>>>(feat, W1, b1, W2, b2, idxs, dense_heat,
                                         rowmap);
  k_nms_hist<<<dim3((HW + CHUNK - 1) / CHUNK, NCLS, NB), 256, 0, stream>>>(
      dense_heat, hist);
  k_thresh<<<NB, 256, 0, stream>>>(hist, selT);
  k_collect<<<dim3((HW + 255) / 256, NCLS, NB), 256, 0, stream>>>(
      dense_heat, selT, sel, sel_cnt);
  k_final<<<NB, 256, 0, stream>>>(sel, sel_cnt, dense_heat, rowmap, feat, Wc, bc,
                                  out);
}